// Round 3
// baseline (523.790 us; speedup 1.0000x reference)
//
#include <hip/hip_runtime.h>
#include <cstdint>
#include <cstddef>

// ---- problem constants (B=2, S=2048, D=1024, F=4096, H=16, dk=64) ----
#define SEQ 2048
#define DMODEL 1024
#define FDIM 4096
#define NH 16
#define DK 64
#define MROWS 4096   // B*S

typedef __attribute__((ext_vector_type(8))) short short8;   // 8 bf16
typedef __attribute__((ext_vector_type(4))) short s16x4;
typedef __attribute__((ext_vector_type(4))) float f32x4;

__device__ __forceinline__ short f2bf(float f) {
    unsigned u = __float_as_uint(f);
    u += 0x7FFFu + ((u >> 16) & 1u);          // RNE
    return (short)(u >> 16);
}

__device__ __forceinline__ void gload_lds16(const void* g, void* l) {
    __builtin_amdgcn_global_load_lds(
        (const __attribute__((address_space(1))) void*)g,
        (__attribute__((address_space(3))) void*)l,
        16, 0, 0);
}

// ---------------- elementwise cast f32 -> bf16 (float4 per thread) ----------------
__global__ __launch_bounds__(256) void cast_kernel(const float* __restrict__ in,
                                                   short* __restrict__ out, int n4) {
    int i = blockIdx.x * 256 + threadIdx.x;
    if (i < n4) {
        float4 v = ((const float4*)in)[i];
        s16x4 ob = { f2bf(v.x), f2bf(v.y), f2bf(v.z), f2bf(v.w) };
        *(s16x4*)(out + (size_t)i * 4) = ob;
    }
}

// ---------------- transpose + cast: in [R][C] f32 -> out [C][R] bf16 ----------------
__global__ void transpose_cast(const float* __restrict__ in, short* __restrict__ out,
                               int R, int C) {
    __shared__ float tile[32][33];
    const int c0 = blockIdx.x * 32, r0 = blockIdx.y * 32;
    const int tx = threadIdx.x, ty = threadIdx.y;
#pragma unroll
    for (int jj = 0; jj < 4; jj++) {
        int j = jj * 8 + ty;
        tile[j][tx] = in[(size_t)(r0 + j) * C + c0 + tx];
    }
    __syncthreads();
#pragma unroll
    for (int jj = 0; jj < 4; jj++) {
        int j = jj * 8 + ty;
        out[(size_t)(c0 + j) * R + r0 + tx] = f2bf(tile[tx][j]);
    }
}

// ---------------- GEMM: C[M][N] = A[M][K](bf16) * Bt[N][K](bf16)^T, fused epilogues ----
#define MODE_QKV 0
#define MODE_O   1
#define MODE_H   2
#define MODE_F   3

__global__ __launch_bounds__(256) void gemm_bt(
    const short* __restrict__ A, const short* __restrict__ Bt,
    const int M, const int N, const int K, const int mode,
    const float* __restrict__ p0, const float* __restrict__ p1,
    void* __restrict__ outp)
{
    __shared__ __align__(16) short ldsA[128 * 32];
    __shared__ __align__(16) short ldsB[128 * 32];
    const int t = threadIdx.x;
    const int nbx = N >> 7;
    const int bx = blockIdx.x % nbx;
    const int by = blockIdx.x / nbx;
    const int brow = by << 7, bcol = bx << 7;
    const int l = t & 63, w = t >> 6;
    const int wr = w >> 1, wc = w & 1;        // 2x2 wave grid, 64x64 out each
    const int lr = l & 15, lk = l >> 4;
    const int sr = t >> 2, sc8 = (t & 3) << 3; // staging row / col8

    f32x4 acc[4][4] = {};

    const short* gA = A + (size_t)(brow + sr) * K + sc8;
    const short* gB = Bt + (size_t)(bcol + sr) * K + sc8;

    for (int k0 = 0; k0 < K; k0 += 32) {
        gload_lds16(gA + k0,                     &ldsA[t * 8]);
        gload_lds16(gA + (size_t)64 * K + k0,    &ldsA[2048 + t * 8]);
        gload_lds16(gB + k0,                     &ldsB[t * 8]);
        gload_lds16(gB + (size_t)64 * K + k0,    &ldsB[2048 + t * 8]);
        __syncthreads();
        short8 af[4], bfr[4];
#pragma unroll
        for (int i = 0; i < 4; i++)
            af[i] = *(const short8*)&ldsA[(wr * 64 + i * 16 + lr) * 32 + lk * 8];
#pragma unroll
        for (int j = 0; j < 4; j++)
            bfr[j] = *(const short8*)&ldsB[(wc * 64 + j * 16 + lr) * 32 + lk * 8];
#pragma unroll
        for (int i = 0; i < 4; i++)
#pragma unroll
            for (int j = 0; j < 4; j++)
                acc[i][j] = __builtin_amdgcn_mfma_f32_16x16x32_bf16(af[i], bfr[j], acc[i][j], 0, 0, 0);
        __syncthreads();
    }

    float gate = 0.f;
    if (mode == MODE_O) gate = 1.f / (1.f + expf(-cosf(p1[0])));

#pragma unroll
    for (int i = 0; i < 4; i++) {
        const int mrow0 = brow + wr * 64 + i * 16 + lk * 4;
#pragma unroll
        for (int j = 0; j < 4; j++) {
            const int gcol = bcol + wc * 64 + j * 16 + lr;
#pragma unroll
            for (int r = 0; r < 4; r++) {
                const int m = mrow0 + r;
                float v = acc[i][j][r];
                if (mode == MODE_QKV) {
                    // gcol in [0,3072): 0=Q,1=K,2=V
                    int which = gcol >> 10;
                    int nn = gcol & 1023;
                    int h = nn >> 6, d = nn & 63;
                    int b = m >> 11, s = m & 2047;
                    if (which == 0) v *= 0.125f;   // 1/sqrt(dk) folded into Q
                    size_t idx = (which == 2)
                        ? ((((size_t)(b * NH + h)) * DK + d) * SEQ + s)    // V^T [B,H,dk,S]
                        : ((((size_t)(b * NH + h)) * SEQ + s) * DK + d);   // Q,K [B,H,S,dk]
                    ((short*)outp)[(size_t)which * ((size_t)MROWS * DMODEL) + idx] = f2bf(v);
                } else if (mode == MODE_O) {
                    size_t idx = (size_t)m * N + gcol;
                    ((float*)outp)[idx] = p0[idx] + gate * v;              // x + gate*attn
                } else if (mode == MODE_H) {
                    float hv = v + p0[gcol];
                    ((short*)outp)[(size_t)m * N + gcol] = f2bf(hv > 0.f ? hv : 0.f); // relu
                } else { // MODE_F
                    size_t idx = (size_t)m * N + gcol;
                    ((float*)outp)[idx] = v + p0[gcol] + p1[idx];          // + b2 + x1
                }
            }
        }
    }
}

// ---------------- flash attention: per (b,h,qtile64); K/V/P LDS XOR-swizzled ---------
__global__ __launch_bounds__(256) void attn_kernel(
    const short* __restrict__ q, const short* __restrict__ k,
    const short* __restrict__ vt, short* __restrict__ ctx)
{
    __shared__ __align__(16) short ldsK[64 * 64];
    __shared__ __align__(16) short ldsV[64 * 64];
    __shared__ __align__(16) short ldsP[64 * 64];
    const int t = threadIdx.x;
    const int w = t >> 6, l = t & 63, lr = l & 15, lk = l >> 4;
    const int bh = blockIdx.x >> 5;
    const int qt = blockIdx.x & 31;
    const int b = bh >> 4, h = bh & 15;
    const size_t koff = (size_t)bh * SEQ * DK;
    const size_t voff = (size_t)bh * DK * SEQ;

    // Q fragments stay in registers for the whole kernel (rows qt*64 + w*16 + lr)
    const int qrow = qt * 64 + w * 16 + lr;
    short8 aq[2];
    aq[0] = *(const short8*)&q[koff + (size_t)qrow * DK + lk * 8];
    aq[1] = *(const short8*)&q[koff + (size_t)qrow * DK + 32 + lk * 8];

    f32x4 o[4] = {};
    float mrow[4] = {-1e30f, -1e30f, -1e30f, -1e30f};
    float den[4] = {0.f, 0.f, 0.f, 0.f};

    // staging: chunk L=c*256+t -> lds row = c*32 + (t>>3), col16 = t&7.
    // XOR-swizzle: data col8 stored at position col8 ^ (row&7) -> pre-swizzle the SOURCE.
    const int strow = t >> 3;
    const int c8 = (t & 7) ^ (strow & 7);      // (strow+32)&7 == strow&7
    const short* gK0 = k + koff + (size_t)strow * DK + c8 * 8;
    const short* gV0 = vt + voff + (size_t)strow * SEQ + c8 * 8;

    for (int s0 = 0; s0 < SEQ; s0 += 64) {
        gload_lds16(gK0 + (size_t)s0 * DK,        &ldsK[t * 8]);
        gload_lds16(gK0 + (size_t)(s0 + 32) * DK, &ldsK[2048 + t * 8]);
        gload_lds16(gV0 + s0,                     &ldsV[t * 8]);
        gload_lds16(gV0 + s0 + (size_t)32 * SEQ,  &ldsV[2048 + t * 8]);
        __syncthreads();

        // S = Q K^T (scale already folded into Q)
        f32x4 sc[4] = {};
#pragma unroll
        for (int kk = 0; kk < 2; kk++) {
#pragma unroll
            for (int nt = 0; nt < 4; nt++) {
                const int row = nt * 16 + lr;
                short8 bk = *(const short8*)&ldsK[row * 64 + (((kk * 4 + lk) ^ (row & 7)) * 8)];
                sc[nt] = __builtin_amdgcn_mfma_f32_16x16x32_bf16(aq[kk], bk, sc[nt], 0, 0, 0);
            }
        }

        // online softmax; lane covers rows lk*4+r, cols nt*16+lr; 16-lane row groups
#pragma unroll
        for (int r = 0; r < 4; r++) {
            float pm = fmaxf(fmaxf(sc[0][r], sc[1][r]), fmaxf(sc[2][r], sc[3][r]));
            pm = fmaxf(pm, __shfl_xor(pm, 1));
            pm = fmaxf(pm, __shfl_xor(pm, 2));
            pm = fmaxf(pm, __shfl_xor(pm, 4));
            pm = fmaxf(pm, __shfl_xor(pm, 8));
            float mnew = fmaxf(mrow[r], pm);
            float scale = __expf(mrow[r] - mnew);
            float ps = 0.f;
#pragma unroll
            for (int nt = 0; nt < 4; nt++) {
                float p = __expf(sc[nt][r] - mnew);
                sc[nt][r] = p;
                ps += p;
            }
            ps += __shfl_xor(ps, 1);
            ps += __shfl_xor(ps, 2);
            ps += __shfl_xor(ps, 4);
            ps += __shfl_xor(ps, 8);
            den[r] = den[r] * scale + ps;
            mrow[r] = mnew;
#pragma unroll
            for (int nt = 0; nt < 4; nt++) o[nt][r] *= scale;
        }

        // P -> LDS bf16 (swizzled same as K/V), own-wave region only
#pragma unroll
        for (int r = 0; r < 4; r++) {
            const int prow = w * 16 + lk * 4 + r;
#pragma unroll
            for (int nt = 0; nt < 4; nt++) {
                const int col16 = nt * 2 + (lr >> 3);
                const int sw = col16 ^ (prow & 7);
                ldsP[prow * 64 + sw * 8 + (lr & 7)] = f2bf(sc[nt][r]);
            }
        }

        // O += P V
#pragma unroll
        for (int kk = 0; kk < 2; kk++) {
            const int prow2 = w * 16 + lr;
            short8 pa = *(const short8*)&ldsP[prow2 * 64 + (((kk * 4 + lk) ^ (prow2 & 7)) * 8)];
#pragma unroll
            for (int nt = 0; nt < 4; nt++) {
                const int vrow = nt * 16 + lr;
                short8 bv = *(const short8*)&ldsV[vrow * 64 + (((kk * 4 + lk) ^ (vrow & 7)) * 8)];
                o[nt] = __builtin_amdgcn_mfma_f32_16x16x32_bf16(pa, bv, o[nt], 0, 0, 0);
            }
        }
        __syncthreads();
    }

    // epilogue: /= den, write ctx [B,S,H*dk] bf16
#pragma unroll
    for (int r = 0; r < 4; r++) {
        const float inv = 1.f / den[r];
        const int s = qt * 64 + w * 16 + lk * 4 + r;
        const size_t base = ((size_t)b * SEQ + s) * DMODEL + h * DK;
#pragma unroll
        for (int nt = 0; nt < 4; nt++)
            ctx[base + nt * 16 + lr] = f2bf(o[nt][r] * inv);
    }
}

// ---------------- LayerNorm over D=1024; optional bf16 + f32 outputs ----------------
__global__ __launch_bounds__(256) void ln_kernel(
    const float* __restrict__ y, const float* __restrict__ g,
    const float* __restrict__ bb, short* __restrict__ out_bf,
    float* __restrict__ out_f)
{
    const int row = blockIdx.x;
    const int t = threadIdx.x;
    const float4 v = ((const float4*)(y + (size_t)row * DMODEL))[t];
    float s = v.x + v.y + v.z + v.w;
    float ss = v.x * v.x + v.y * v.y + v.z * v.z + v.w * v.w;
#pragma unroll
    for (int off = 32; off > 0; off >>= 1) {
        s  += __shfl_down(s, off);
        ss += __shfl_down(ss, off);
    }
    __shared__ float red[8];
    const int w = t >> 6, l = t & 63;
    if (l == 0) { red[w] = s; red[4 + w] = ss; }
    __syncthreads();
    s  = red[0] + red[1] + red[2] + red[3];
    ss = red[4] + red[5] + red[6] + red[7];
    const float mu = s * (1.f / DMODEL);
    const float var = ss * (1.f / DMODEL) - mu * mu;
    const float rstd = rsqrtf(var + 1e-5f);
    const float4 gg = ((const float4*)g)[t];
    const float4 bv = ((const float4*)bb)[t];
    float o0 = (v.x - mu) * rstd * gg.x + bv.x;
    float o1 = (v.y - mu) * rstd * gg.y + bv.y;
    float o2 = (v.z - mu) * rstd * gg.z + bv.z;
    float o3 = (v.w - mu) * rstd * gg.w + bv.w;
    if (out_f) ((float4*)(out_f + (size_t)row * DMODEL))[t] = make_float4(o0, o1, o2, o3);
    if (out_bf) {
        s16x4 ob = { f2bf(o0), f2bf(o1), f2bf(o2), f2bf(o3) };
        *(s16x4*)(out_bf + (size_t)row * DMODEL + t * 4) = ob;
    }
}

// ---------------- launcher ----------------
extern "C" void kernel_launch(void* const* d_in, const int* in_sizes, int n_in,
                              void* d_out, int out_size, void* d_ws, size_t ws_size,
                              hipStream_t stream)
{
    const float* x     = (const float*)d_in[0];
    const float* wq    = (const float*)d_in[1];
    const float* wk    = (const float*)d_in[2];
    const float* wv    = (const float*)d_in[3];
    const float* wo    = (const float*)d_in[4];
    const float* w1    = (const float*)d_in[5];
    const float* b1    = (const float*)d_in[6];
    const float* w2    = (const float*)d_in[7];
    const float* b2    = (const float*)d_in[8];
    const float* ln1_g = (const float*)d_in[9];
    const float* ln1_b = (const float*)d_in[10];
    const float* ln2_g = (const float*)d_in[11];
    const float* ln2_b = (const float*)d_in[12];
    const float* theta = (const float*)d_in[13];

    // workspace layout (shorts region then floats region); hb aliases q/k/v/ctx
    short* wsS   = (short*)d_ws;
    short* xb    = wsS;                    // 4,194,304
    short* wqkvT = wsS + 4194304;          // 3 x 1,048,576  (contiguous => N=3072 GEMM)
    short* woT   = wsS + 7340032;          // 1,048,576
    short* w1T   = wsS + 8388608;          // 4,194,304  [4096][1024]
    short* w2T   = wsS + 12582912;         // 4,194,304  [1024][4096]
    short* qb    = wsS + 16777216;         // q,k,v,ctx: 4 x 4,194,304 (hb alias region)
    short* ctxb  = wsS + 29360128;
    short* x1b   = wsS + 33554432;         // 4,194,304
    short* hb    = qb;                     // [4096][4096] bf16, aliases q/k/v/ctx
    float* fbase = (float*)((char*)d_ws + 75497472);
    float* y1    = fbase;                  // 4,194,304 f32 (also y2)
    float* x1f   = fbase + 4194304;        // 4,194,304 f32
    if (ws_size < 109051904) return;       // need ~109 MB

    dim3 t32(32, 8, 1);
    cast_kernel<<<4096, 256, 0, stream>>>(x, xb, 1048576);
    transpose_cast<<<dim3(32, 32), t32, 0, stream>>>(wq, wqkvT,           DMODEL, DMODEL);
    transpose_cast<<<dim3(32, 32), t32, 0, stream>>>(wk, wqkvT + 1048576, DMODEL, DMODEL);
    transpose_cast<<<dim3(32, 32), t32, 0, stream>>>(wv, wqkvT + 2097152, DMODEL, DMODEL);
    transpose_cast<<<dim3(32, 32), t32, 0, stream>>>(wo, woT,             DMODEL, DMODEL);
    transpose_cast<<<dim3(128, 32), t32, 0, stream>>>(w1, w1T, DMODEL, FDIM);
    transpose_cast<<<dim3(32, 128), t32, 0, stream>>>(w2, w2T, FDIM, DMODEL);

    gemm_bt<<<768, 256, 0, stream>>>(xb, wqkvT, MROWS, 3072, DMODEL, MODE_QKV,
                                     nullptr, nullptr, qb);
    attn_kernel<<<1024, 256, 0, stream>>>(qb, qb + 4194304, qb + 8388608, ctxb);
    gemm_bt<<<256, 256, 0, stream>>>(ctxb, woT, MROWS, DMODEL, DMODEL, MODE_O,
                                     x, theta, y1);
    ln_kernel<<<4096, 256, 0, stream>>>(y1, ln1_g, ln1_b, x1b, x1f);
    gemm_bt<<<1024, 256, 0, stream>>>(x1b, w1T, MROWS, FDIM, DMODEL, MODE_H,
                                      b1, nullptr, hb);
    gemm_bt<<<256, 256, 0, stream>>>(hb, w2T, MROWS, DMODEL, FDIM, MODE_F,
                                     b2, x1f, y1);
    ln_kernel<<<4096, 256, 0, stream>>>(y1, ln2_g, ln2_b, nullptr, (float*)d_out);
}

// Round 6
// 487.949 us; speedup vs baseline: 1.0735x; 1.0735x over previous
//
#include <hip/hip_runtime.h>
#include <cstdint>
#include <cstddef>

// ---- problem constants (B=2, S=2048, D=1024, F=4096, H=16, dk=64) ----
#define SEQ 2048
#define DMODEL 1024
#define FDIM 4096
#define NH 16
#define DK 64
#define MROWS 4096   // B*S

typedef __attribute__((ext_vector_type(8))) short short8;   // 8 bf16
typedef __attribute__((ext_vector_type(4))) short s16x4;
typedef __attribute__((ext_vector_type(4))) float f32x4;

__device__ __forceinline__ short f2bf(float f) {
    unsigned u = __float_as_uint(f);
    u += 0x7FFFu + ((u >> 16) & 1u);          // RNE
    return (short)(u >> 16);
}

__device__ __forceinline__ void gload_lds16(const void* g, void* l) {
    __builtin_amdgcn_global_load_lds(
        (const __attribute__((address_space(1))) void*)g,
        (__attribute__((address_space(3))) void*)l,
        16, 0, 0);
}

// ---------------- elementwise cast f32 -> bf16 (float4 per thread) ----------------
__global__ __launch_bounds__(256) void cast_kernel(const float* __restrict__ in,
                                                   short* __restrict__ out, int n4) {
    int i = blockIdx.x * 256 + threadIdx.x;
    if (i < n4) {
        float4 v = ((const float4*)in)[i];
        s16x4 ob = { f2bf(v.x), f2bf(v.y), f2bf(v.z), f2bf(v.w) };
        *(s16x4*)(out + (size_t)i * 4) = ob;
    }
}

// ---------------- transpose + cast: in [R][C] f32 -> out [C][R] bf16 ----------------
__global__ void transpose_cast(const float* __restrict__ in, short* __restrict__ out,
                               int R, int C) {
    __shared__ float tile[32][33];
    const int c0 = blockIdx.x * 32, r0 = blockIdx.y * 32;
    const int tx = threadIdx.x, ty = threadIdx.y;
#pragma unroll
    for (int jj = 0; jj < 4; jj++) {
        int j = jj * 8 + ty;
        tile[j][tx] = in[(size_t)(r0 + j) * C + c0 + tx];
    }
    __syncthreads();
#pragma unroll
    for (int jj = 0; jj < 4; jj++) {
        int j = jj * 8 + ty;
        out[(size_t)(c0 + j) * R + r0 + tx] = f2bf(tile[tx][j]);
    }
}

// ---------------- GEMM: C[M][N] = A[M][K](bf16) * Bt[N][K](bf16)^T, fused epilogues ----
// BM=128 always; BN is a template param (128: 2x2 waves of 64x64; 64: 4 waves of 32x64).
// T1: bijective XCD swizzle (requires gridDim.x % 8 == 0) -> each XCD owns a
// contiguous chunk of tile-space so A-panels are fetched once per XCD.
#define MODE_QKV 0
#define MODE_O   1
#define MODE_H   2
#define MODE_F   3

template<int BN>
__global__ __launch_bounds__(256) void gemm_bt(
    const short* __restrict__ A, const short* __restrict__ Bt,
    const int M, const int N, const int K, const int mode,
    const float* __restrict__ p0, const float* __restrict__ p1,
    void* __restrict__ outp)
{
    __shared__ __align__(16) short ldsA[128 * 32];
    __shared__ __align__(16) short ldsB[BN * 32];
    const int t = threadIdx.x;
    const int nbx = N / BN;
    const int q8 = gridDim.x >> 3;                       // chunk per XCD
    const int swz = (blockIdx.x & 7) * q8 + (blockIdx.x >> 3);
    const int bx = swz % nbx;
    const int by = swz / nbx;
    const int brow = by << 7, bcol = bx * BN;
    const int l = t & 63, w = t >> 6;
    const int lr = l & 15, lk = l >> 4;
    const int sr = t >> 2, sc8 = (t & 3) << 3;           // staging row / col8

    constexpr int RF = (BN == 128) ? 4 : 2;              // 16-row frags per wave
    const int wrow = (BN == 128) ? ((w >> 1) * 64) : (w * 32);
    const int wcol = (BN == 128) ? ((w & 1) * 64) : 0;

    f32x4 acc[RF][4] = {};

    const short* gA = A + (size_t)(brow + sr) * K + sc8;
    const short* gB = Bt + (size_t)(bcol + sr) * K + sc8;

    for (int k0 = 0; k0 < K; k0 += 32) {
        gload_lds16(gA + k0,                     &ldsA[t * 8]);
        gload_lds16(gA + (size_t)64 * K + k0,    &ldsA[2048 + t * 8]);
        gload_lds16(gB + k0,                     &ldsB[t * 8]);
        if (BN == 128)
            gload_lds16(gB + (size_t)64 * K + k0, &ldsB[2048 + t * 8]);
        __syncthreads();
        short8 af[RF], bfr[4];
#pragma unroll
        for (int i = 0; i < RF; i++)
            af[i] = *(const short8*)&ldsA[(wrow + i * 16 + lr) * 32 + lk * 8];
#pragma unroll
        for (int j = 0; j < 4; j++)
            bfr[j] = *(const short8*)&ldsB[(wcol + j * 16 + lr) * 32 + lk * 8];
#pragma unroll
        for (int i = 0; i < RF; i++)
#pragma unroll
            for (int j = 0; j < 4; j++)
                acc[i][j] = __builtin_amdgcn_mfma_f32_16x16x32_bf16(af[i], bfr[j], acc[i][j], 0, 0, 0);
        __syncthreads();
    }

    float gate = 0.f;
    if (mode == MODE_O) gate = 1.f / (1.f + expf(-cosf(p1[0])));

#pragma unroll
    for (int i = 0; i < RF; i++) {
        const int mrow0 = brow + wrow + i * 16 + lk * 4;
#pragma unroll
        for (int j = 0; j < 4; j++) {
            const int gcol = bcol + wcol + j * 16 + lr;
#pragma unroll
            for (int r = 0; r < 4; r++) {
                const int m = mrow0 + r;
                float v = acc[i][j][r];
                if (mode == MODE_QKV) {
                    // gcol in [0,3072): 0=Q,1=K,2=V
                    int which = gcol >> 10;
                    int nn = gcol & 1023;
                    int h = nn >> 6, d = nn & 63;
                    int b = m >> 11, s = m & 2047;
                    if (which == 0) v *= 0.125f;   // 1/sqrt(dk) folded into Q
                    size_t idx = (which == 2)
                        ? ((((size_t)(b * NH + h)) * DK + d) * SEQ + s)    // V^T [B,H,dk,S]
                        : ((((size_t)(b * NH + h)) * SEQ + s) * DK + d);   // Q,K [B,H,S,dk]
                    ((short*)outp)[(size_t)which * ((size_t)MROWS * DMODEL) + idx] = f2bf(v);
                } else if (mode == MODE_O) {
                    size_t idx = (size_t)m * N + gcol;
                    ((float*)outp)[idx] = p0[idx] + gate * v;              // x + gate*attn
                } else if (mode == MODE_H) {
                    float hv = v + p0[gcol];
                    ((short*)outp)[(size_t)m * N + gcol] = f2bf(hv > 0.f ? hv : 0.f); // relu
                } else { // MODE_F
                    size_t idx = (size_t)m * N + gcol;
                    ((float*)outp)[idx] = v + p0[gcol] + p1[idx];          // + b2 + x1
                }
            }
        }
    }
}

// ---------------- flash attention: per (b,h,qtile64); K/V/P LDS XOR-swizzled ---------
__global__ __launch_bounds__(256) void attn_kernel(
    const short* __restrict__ q, const short* __restrict__ k,
    const short* __restrict__ vt, short* __restrict__ ctx)
{
    __shared__ __align__(16) short ldsK[64 * 64];
    __shared__ __align__(16) short ldsV[64 * 64];
    __shared__ __align__(16) short ldsP[64 * 64];
    const int t = threadIdx.x;
    const int w = t >> 6, l = t & 63, lr = l & 15, lk = l >> 4;
    const int bh = blockIdx.x >> 5;
    const int qt = blockIdx.x & 31;
    const int b = bh >> 4, h = bh & 15;
    const size_t koff = (size_t)bh * SEQ * DK;
    const size_t voff = (size_t)bh * DK * SEQ;

    // Q fragments stay in registers for the whole kernel (rows qt*64 + w*16 + lr)
    const int qrow = qt * 64 + w * 16 + lr;
    short8 aq[2];
    aq[0] = *(const short8*)&q[koff + (size_t)qrow * DK + lk * 8];
    aq[1] = *(const short8*)&q[koff + (size_t)qrow * DK + 32 + lk * 8];

    f32x4 o[4] = {};
    float mrow[4] = {-1e30f, -1e30f, -1e30f, -1e30f};
    float den[4] = {0.f, 0.f, 0.f, 0.f};

    // staging: chunk L=c*256+t -> lds row = c*32 + (t>>3), col16 = t&7.
    // XOR-swizzle: data col8 stored at position col8 ^ (row&7) -> pre-swizzle the SOURCE.
    const int strow = t >> 3;
    const int c8 = (t & 7) ^ (strow & 7);      // (strow+32)&7 == strow&7
    const short* gK0 = k + koff + (size_t)strow * DK + c8 * 8;
    const short* gV0 = vt + voff + (size_t)strow * SEQ + c8 * 8;

    for (int s0 = 0; s0 < SEQ; s0 += 64) {
        gload_lds16(gK0 + (size_t)s0 * DK,        &ldsK[t * 8]);
        gload_lds16(gK0 + (size_t)(s0 + 32) * DK, &ldsK[2048 + t * 8]);
        gload_lds16(gV0 + s0,                     &ldsV[t * 8]);
        gload_lds16(gV0 + s0 + (size_t)32 * SEQ,  &ldsV[2048 + t * 8]);
        __syncthreads();

        // S = Q K^T (scale already folded into Q)
        f32x4 sc[4] = {};
#pragma unroll
        for (int kk = 0; kk < 2; kk++) {
#pragma unroll
            for (int nt = 0; nt < 4; nt++) {
                const int row = nt * 16 + lr;
                short8 bk = *(const short8*)&ldsK[row * 64 + (((kk * 4 + lk) ^ (row & 7)) * 8)];
                sc[nt] = __builtin_amdgcn_mfma_f32_16x16x32_bf16(aq[kk], bk, sc[nt], 0, 0, 0);
            }
        }

        // online softmax; lane covers rows lk*4+r, cols nt*16+lr; 16-lane row groups
#pragma unroll
        for (int r = 0; r < 4; r++) {
            float pm = fmaxf(fmaxf(sc[0][r], sc[1][r]), fmaxf(sc[2][r], sc[3][r]));
            pm = fmaxf(pm, __shfl_xor(pm, 1));
            pm = fmaxf(pm, __shfl_xor(pm, 2));
            pm = fmaxf(pm, __shfl_xor(pm, 4));
            pm = fmaxf(pm, __shfl_xor(pm, 8));
            float mnew = fmaxf(mrow[r], pm);
            float scale = __expf(mrow[r] - mnew);
            float ps = 0.f;
#pragma unroll
            for (int nt = 0; nt < 4; nt++) {
                float p = __expf(sc[nt][r] - mnew);
                sc[nt][r] = p;
                ps += p;
            }
            ps += __shfl_xor(ps, 1);
            ps += __shfl_xor(ps, 2);
            ps += __shfl_xor(ps, 4);
            ps += __shfl_xor(ps, 8);
            den[r] = den[r] * scale + ps;
            mrow[r] = mnew;
#pragma unroll
            for (int nt = 0; nt < 4; nt++) o[nt][r] *= scale;
        }

        // P -> LDS bf16 (swizzled same as K/V), own-wave region only
#pragma unroll
        for (int r = 0; r < 4; r++) {
            const int prow = w * 16 + lk * 4 + r;
#pragma unroll
            for (int nt = 0; nt < 4; nt++) {
                const int col16 = nt * 2 + (lr >> 3);
                const int sw = col16 ^ (prow & 7);
                ldsP[prow * 64 + sw * 8 + (lr & 7)] = f2bf(sc[nt][r]);
            }
        }

        // O += P V
#pragma unroll
        for (int kk = 0; kk < 2; kk++) {
            const int prow2 = w * 16 + lr;
            short8 pa = *(const short8*)&ldsP[prow2 * 64 + (((kk * 4 + lk) ^ (prow2 & 7)) * 8)];
#pragma unroll
            for (int nt = 0; nt < 4; nt++) {
                const int vrow = nt * 16 + lr;
                short8 bv = *(const short8*)&ldsV[vrow * 64 + (((kk * 4 + lk) ^ (vrow & 7)) * 8)];
                o[nt] = __builtin_amdgcn_mfma_f32_16x16x32_bf16(pa, bv, o[nt], 0, 0, 0);
            }
        }
        __syncthreads();
    }

    // epilogue: /= den, write ctx [B,S,H*dk] bf16
#pragma unroll
    for (int r = 0; r < 4; r++) {
        const float inv = 1.f / den[r];
        const int s = qt * 64 + w * 16 + lk * 4 + r;
        const size_t base = ((size_t)b * SEQ + s) * DMODEL + h * DK;
#pragma unroll
        for (int nt = 0; nt < 4; nt++)
            ctx[base + nt * 16 + lr] = f2bf(o[nt][r] * inv);
    }
}

// ---------------- LayerNorm over D=1024; optional bf16 + f32 outputs ----------------
__global__ __launch_bounds__(256) void ln_kernel(
    const float* __restrict__ y, const float* __restrict__ g,
    const float* __restrict__ bb, short* __restrict__ out_bf,
    float* __restrict__ out_f)
{
    const int row = blockIdx.x;
    const int t = threadIdx.x;
    const float4 v = ((const float4*)(y + (size_t)row * DMODEL))[t];
    float s = v.x + v.y + v.z + v.w;
    float ss = v.x * v.x + v.y * v.y + v.z * v.z + v.w * v.w;
#pragma unroll
    for (int off = 32; off > 0; off >>= 1) {
        s  += __shfl_down(s, off);
        ss += __shfl_down(ss, off);
    }
    __shared__ float red[8];
    const int w = t >> 6, l = t & 63;
    if (l == 0) { red[w] = s; red[4 + w] = ss; }
    __syncthreads();
    s  = red[0] + red[1] + red[2] + red[3];
    ss = red[4] + red[5] + red[6] + red[7];
    const float mu = s * (1.f / DMODEL);
    const float var = ss * (1.f / DMODEL) - mu * mu;
    const float rstd = rsqrtf(var + 1e-5f);
    const float4 gg = ((const float4*)g)[t];
    const float4 bv = ((const float4*)bb)[t];
    float o0 = (v.x - mu) * rstd * gg.x + bv.x;
    float o1 = (v.y - mu) * rstd * gg.y + bv.y;
    float o2 = (v.z - mu) * rstd * gg.z + bv.z;
    float o3 = (v.w - mu) * rstd * gg.w + bv.w;
    if (out_f) ((float4*)(out_f + (size_t)row * DMODEL))[t] = make_float4(o0, o1, o2, o3);
    if (out_bf) {
        s16x4 ob = { f2bf(o0), f2bf(o1), f2bf(o2), f2bf(o3) };
        *(s16x4*)(out_bf + (size_t)row * DMODEL + t * 4) = ob;
    }
}

// ---------------- launcher ----------------
extern "C" void kernel_launch(void* const* d_in, const int* in_sizes, int n_in,
                              void* d_out, int out_size, void* d_ws, size_t ws_size,
                              hipStream_t stream)
{
    const float* x     = (const float*)d_in[0];
    const float* wq    = (const float*)d_in[1];
    const float* wk    = (const float*)d_in[2];
    const float* wv    = (const float*)d_in[3];
    const float* wo    = (const float*)d_in[4];
    const float* w1    = (const float*)d_in[5];
    const float* b1    = (const float*)d_in[6];
    const float* w2    = (const float*)d_in[7];
    const float* b2    = (const float*)d_in[8];
    const float* ln1_g = (const float*)d_in[9];
    const float* ln1_b = (const float*)d_in[10];
    const float* ln2_g = (const float*)d_in[11];
    const float* ln2_b = (const float*)d_in[12];
    const float* theta = (const float*)d_in[13];

    // workspace layout (shorts region then floats region); hb aliases q/k/v/ctx
    short* wsS   = (short*)d_ws;
    short* xb    = wsS;                    // 4,194,304
    short* wqkvT = wsS + 4194304;          // 3 x 1,048,576  (contiguous => N=3072 GEMM)
    short* woT   = wsS + 7340032;          // 1,048,576
    short* w1T   = wsS + 8388608;          // 4,194,304  [4096][1024]
    short* w2T   = wsS + 12582912;         // 4,194,304  [1024][4096]
    short* qb    = wsS + 16777216;         // q,k,v,ctx: 4 x 4,194,304 (hb alias region)
    short* ctxb  = wsS + 29360128;
    short* x1b   = wsS + 33554432;         // 4,194,304
    short* hb    = qb;                     // [4096][4096] bf16, aliases q/k/v/ctx
    float* fbase = (float*)((char*)d_ws + 75497472);
    float* y1    = fbase;                  // 4,194,304 f32 (also y2)
    float* x1f   = fbase + 4194304;        // 4,194,304 f32
    if (ws_size < 109051904) return;       // need ~109 MB

    dim3 t32(32, 8, 1);
    cast_kernel<<<4096, 256, 0, stream>>>(x, xb, 1048576);
    transpose_cast<<<dim3(32, 32), t32, 0, stream>>>(wq, wqkvT,           DMODEL, DMODEL);
    transpose_cast<<<dim3(32, 32), t32, 0, stream>>>(wk, wqkvT + 1048576, DMODEL, DMODEL);
    transpose_cast<<<dim3(32, 32), t32, 0, stream>>>(wv, wqkvT + 2097152, DMODEL, DMODEL);
    transpose_cast<<<dim3(32, 32), t32, 0, stream>>>(wo, woT,             DMODEL, DMODEL);
    transpose_cast<<<dim3(128, 32), t32, 0, stream>>>(w1, w1T, DMODEL, FDIM);
    transpose_cast<<<dim3(32, 128), t32, 0, stream>>>(w2, w2T, FDIM, DMODEL);

    // QKV: 32x24 = 768 blocks (BN=128, 3/CU)
    gemm_bt<128><<<768, 256, 0, stream>>>(xb, wqkvT, MROWS, 3072, DMODEL, MODE_QKV,
                                          nullptr, nullptr, qb);
    attn_kernel<<<1024, 256, 0, stream>>>(qb, qb + 4194304, qb + 8388608, ctxb);
    // O-proj: 32x16 = 512 blocks (BN=64, 2/CU)
    gemm_bt<64><<<512, 256, 0, stream>>>(ctxb, woT, MROWS, DMODEL, DMODEL, MODE_O,
                                         x, theta, y1);
    ln_kernel<<<4096, 256, 0, stream>>>(y1, ln1_g, ln1_b, x1b, x1f);
    // FFN-1: 32x32 = 1024 blocks (BN=128, 4/CU)
    gemm_bt<128><<<1024, 256, 0, stream>>>(x1b, w1T, MROWS, FDIM, DMODEL, MODE_H,
                                           b1, nullptr, hb);
    // FFN-2: 32x16 = 512 blocks (BN=64, 2/CU)
    gemm_bt<64><<<512, 256, 0, stream>>>(hb, w2T, MROWS, DMODEL, FDIM, MODE_F,
                                         b2, x1f, y1);
    ln_kernel<<<4096, 256, 0, stream>>>(y1, ln2_g, ln2_b, nullptr, (float*)d_out);
}

// Round 14
// 447.558 us; speedup vs baseline: 1.1703x; 1.0902x over previous
//
#include <hip/hip_runtime.h>
#include <cstdint>
#include <cstddef>

// ---- problem constants (B=2, S=2048, D=1024, F=4096, H=16, dk=64) ----
#define SEQ 2048
#define DMODEL 1024
#define FDIM 4096
#define NH 16
#define DK 64
#define MROWS 4096   // B*S

typedef __attribute__((ext_vector_type(8))) short short8;   // 8 bf16
typedef __attribute__((ext_vector_type(4))) short s16x4;
typedef __attribute__((ext_vector_type(4))) float f32x4;

__device__ __forceinline__ short f2bf(float f) {
    unsigned u = __float_as_uint(f);
    u += 0x7FFFu + ((u >> 16) & 1u);          // RNE
    return (short)(u >> 16);
}

__device__ __forceinline__ void gload_lds16(const void* g, void* l) {
    __builtin_amdgcn_global_load_lds(
        (const __attribute__((address_space(1))) void*)g,
        (__attribute__((address_space(3))) void*)l,
        16, 0, 0);
}

// ---------------- elementwise cast f32 -> bf16 (float4 per thread) ----------------
__global__ __launch_bounds__(256) void cast_kernel(const float* __restrict__ in,
                                                   short* __restrict__ out, int n4) {
    int i = blockIdx.x * 256 + threadIdx.x;
    if (i < n4) {
        float4 v = ((const float4*)in)[i];
        s16x4 ob = { f2bf(v.x), f2bf(v.y), f2bf(v.z), f2bf(v.w) };
        *(s16x4*)(out + (size_t)i * 4) = ob;
    }
}

// ---------------- transpose + cast: in [R][C] f32 -> out [C][R] bf16 ----------------
__global__ void transpose_cast(const float* __restrict__ in, short* __restrict__ out,
                               int R, int C) {
    __shared__ float tile[32][33];
    const int c0 = blockIdx.x * 32, r0 = blockIdx.y * 32;
    const int tx = threadIdx.x, ty = threadIdx.y;
#pragma unroll
    for (int jj = 0; jj < 4; jj++) {
        int j = jj * 8 + ty;
        tile[j][tx] = in[(size_t)(r0 + j) * C + c0 + tx];
    }
    __syncthreads();
#pragma unroll
    for (int jj = 0; jj < 4; jj++) {
        int j = jj * 8 + ty;
        out[(size_t)(c0 + j) * R + r0 + tx] = f2bf(tile[tx][j]);
    }
}

// ---------------- GEMM: C[M][N] = A[M][K](bf16) * Bt[N][K](bf16)^T, fused epilogues ----
// BM=128 always; BN is a template param (128: 2x2 waves of 64x64; 64: 4 waves of 32x64).
// T1: bijective XCD swizzle (requires gridDim.x % 8 == 0).
#define MODE_QKV 0
#define MODE_O   1
#define MODE_H   2
#define MODE_F   3

template<int BN>
__global__ __launch_bounds__(256) void gemm_bt(
    const short* __restrict__ A, const short* __restrict__ Bt,
    const int M, const int N, const int K, const int mode,
    const float* __restrict__ p0, const float* __restrict__ p1,
    void* __restrict__ outp)
{
    __shared__ __align__(16) short ldsA[128 * 32];
    __shared__ __align__(16) short ldsB[BN * 32];
    const int t = threadIdx.x;
    const int nbx = N / BN;
    const int q8 = gridDim.x >> 3;                       // chunk per XCD
    const int swz = (blockIdx.x & 7) * q8 + (blockIdx.x >> 3);
    const int bx = swz % nbx;
    const int by = swz / nbx;
    const int brow = by << 7, bcol = bx * BN;
    const int l = t & 63, w = t >> 6;
    const int lr = l & 15, lk = l >> 4;
    const int sr = t >> 2, sc8 = (t & 3) << 3;           // staging row / col8

    constexpr int RF = (BN == 128) ? 4 : 2;              // 16-row frags per wave
    const int wrow = (BN == 128) ? ((w >> 1) * 64) : (w * 32);
    const int wcol = (BN == 128) ? ((w & 1) * 64) : 0;

    f32x4 acc[RF][4] = {};

    const short* gA = A + (size_t)(brow + sr) * K + sc8;
    const short* gB = Bt + (size_t)(bcol + sr) * K + sc8;

    for (int k0 = 0; k0 < K; k0 += 32) {
        gload_lds16(gA + k0,                     &ldsA[t * 8]);
        gload_lds16(gA + (size_t)64 * K + k0,    &ldsA[2048 + t * 8]);
        gload_lds16(gB + k0,                     &ldsB[t * 8]);
        if (BN == 128)
            gload_lds16(gB + (size_t)64 * K + k0, &ldsB[2048 + t * 8]);
        __syncthreads();
        short8 af[RF], bfr[4];
#pragma unroll
        for (int i = 0; i < RF; i++)
            af[i] = *(const short8*)&ldsA[(wrow + i * 16 + lr) * 32 + lk * 8];
#pragma unroll
        for (int j = 0; j < 4; j++)
            bfr[j] = *(const short8*)&ldsB[(wcol + j * 16 + lr) * 32 + lk * 8];
#pragma unroll
        for (int i = 0; i < RF; i++)
#pragma unroll
            for (int j = 0; j < 4; j++)
                acc[i][j] = __builtin_amdgcn_mfma_f32_16x16x32_bf16(af[i], bfr[j], acc[i][j], 0, 0, 0);
        __syncthreads();
    }

    float gate = 0.f;
    if (mode == MODE_O) gate = 1.f / (1.f + expf(-cosf(p1[0])));

#pragma unroll
    for (int i = 0; i < RF; i++) {
        const int mrow0 = brow + wrow + i * 16 + lk * 4;
#pragma unroll
        for (int j = 0; j < 4; j++) {
            const int gcol = bcol + wcol + j * 16 + lr;
#pragma unroll
            for (int r = 0; r < 4; r++) {
                const int m = mrow0 + r;
                float v = acc[i][j][r];
                if (mode == MODE_QKV) {
                    // gcol in [0,3072): 0=Q,1=K,2=V
                    int which = gcol >> 10;
                    int nn = gcol & 1023;
                    int h = nn >> 6, d = nn & 63;
                    int b = m >> 11, s = m & 2047;
                    if (which == 0) v *= 0.125f;   // 1/sqrt(dk) folded into Q
                    size_t idx = (which == 2)
                        ? ((((size_t)(b * NH + h)) * DK + d) * SEQ + s)    // V^T [B,H,dk,S]
                        : ((((size_t)(b * NH + h)) * SEQ + s) * DK + d);   // Q,K [B,H,S,dk]
                    ((short*)outp)[(size_t)which * ((size_t)MROWS * DMODEL) + idx] = f2bf(v);
                } else if (mode == MODE_O) {
                    size_t idx = (size_t)m * N + gcol;
                    ((float*)outp)[idx] = p0[idx] + gate * v;              // x + gate*attn
                } else if (mode == MODE_H) {
                    float hv = v + p0[gcol];
                    ((short*)outp)[(size_t)m * N + gcol] = f2bf(hv > 0.f ? hv : 0.f); // relu
                } else { // MODE_F
                    size_t idx = (size_t)m * N + gcol;
                    ((float*)outp)[idx] = v + p0[gcol] + p1[idx];          // + b2 + x1
                }
            }
        }
    }
}

// ---------------- flash attention v2: swapped QK^T, in-lane softmax, dbuf K/V -------
// Per (b,h,qtile64), 4 waves x 16 q-rows. Each lane's softmax state covers q = lr.
// S^T = mfma(A=K, B=Q): lane holds S[kv=nt*16+lk*4+r][q=lr] -> row reduce is 15
// in-lane ops + 2 shuffles. P repacked to bf16 dwords, written to per-wave LDS
// (XOR-swizzled, 2-way max conflict), read back as PV A-frags (2 x b128).
// K/V double-buffered: stage t+1 before compute t, one barrier per iter.
// Defer-max (T13): skip O-rescale while tile max stays within 8 of running max.
__global__ __launch_bounds__(256) void attn_kernel(
    const short* __restrict__ q, const short* __restrict__ k,
    const short* __restrict__ vt, short* __restrict__ ctx)
{
    __shared__ __align__(16) short ldsK[2 * 64 * 64];
    __shared__ __align__(16) short ldsV[2 * 64 * 64];
    __shared__ __align__(16) unsigned int ldsP[4 * 512];   // 4 waves x 16q x 32 dwords
    const int t = threadIdx.x;
    const int w = t >> 6, l = t & 63, lr = l & 15, lk = l >> 4;
    const int bh = blockIdx.x >> 5;
    const int qt = blockIdx.x & 31;
    const int b = bh >> 4, h = bh & 15;
    const size_t koff = (size_t)bh * SEQ * DK;
    const size_t voff = (size_t)bh * DK * SEQ;

    // Q fragment (B-operand: col=q=lr, k=d) — same register layout as A-frag
    const int qrow = qt * 64 + w * 16 + lr;
    short8 aq[2];
    aq[0] = *(const short8*)&q[koff + (size_t)qrow * DK + lk * 8];
    aq[1] = *(const short8*)&q[koff + (size_t)qrow * DK + 32 + lk * 8];

    f32x4 o[4] = {};
    float mrow = -1e30f, den = 0.f;

    // staging: lds row = t>>3, chunk8 pre-swizzled on the SOURCE (rule #21)
    const int strow = t >> 3;
    const int c8 = (t & 7) ^ (strow & 7);
    const short* gK0 = k + koff + (size_t)strow * DK + c8 * 8;
    const short* gV0 = vt + voff + (size_t)strow * SEQ + c8 * 8;

    // prologue: stage tile 0 into buffer 0
    gload_lds16(gK0,                    &ldsK[t * 8]);
    gload_lds16(gK0 + (size_t)32 * DK,  &ldsK[2048 + t * 8]);
    gload_lds16(gV0,                    &ldsV[t * 8]);
    gload_lds16(gV0 + (size_t)32 * SEQ, &ldsV[2048 + t * 8]);
    __syncthreads();

    unsigned int* Pw = &ldsP[w * 512 + lr * 32];
    int cur = 0;
    for (int it = 0; it < SEQ / 64; ++it) {
        // issue next-tile staging early (hides under compute; drained by barrier)
        const int s0n = (it + 1) * 64;
        if (s0n < SEQ) {
            const int nb = cur ^ 1;
            gload_lds16(gK0 + (size_t)s0n * DK,        &ldsK[nb * 4096 + t * 8]);
            gload_lds16(gK0 + (size_t)(s0n + 32) * DK, &ldsK[nb * 4096 + 2048 + t * 8]);
            gload_lds16(gV0 + s0n,                     &ldsV[nb * 4096 + t * 8]);
            gload_lds16(gV0 + s0n + (size_t)32 * SEQ,  &ldsV[nb * 4096 + 2048 + t * 8]);
        }
        const short* bK = &ldsK[cur * 4096];
        const short* bV = &ldsV[cur * 4096];

        // S^T = K · Q^T (scale folded into Q): sc[nt][r] = S[kv=nt*16+lk*4+r][q=lr]
        f32x4 sc[4] = {};
#pragma unroll
        for (int kk = 0; kk < 2; kk++) {
#pragma unroll
            for (int nt = 0; nt < 4; nt++) {
                const int row = nt * 16 + lr;
                short8 kf = *(const short8*)&bK[row * 64 + (((kk * 4 + lk) ^ (row & 7)) * 8)];
                sc[nt] = __builtin_amdgcn_mfma_f32_16x16x32_bf16(kf, aq[kk], sc[nt], 0, 0, 0);
            }
        }

        // row max: 15 in-lane + 2 cross-lane (lanes lr,+16,+32,+48 share q)
        float pm = fmaxf(fmaxf(fmaxf(sc[0][0], sc[0][1]), fmaxf(sc[0][2], sc[0][3])),
                   fmaxf(fmaxf(fmaxf(sc[1][0], sc[1][1]), fmaxf(sc[1][2], sc[1][3])),
                   fmaxf(fmaxf(fmaxf(sc[2][0], sc[2][1]), fmaxf(sc[2][2], sc[2][3])),
                         fmaxf(fmaxf(sc[3][0], sc[3][1]), fmaxf(sc[3][2], sc[3][3])))));
        pm = fmaxf(pm, __shfl_xor(pm, 16));
        pm = fmaxf(pm, __shfl_xor(pm, 32));
        const bool defer = __all(pm <= mrow + 8.0f);     // T13, THR=8
        const float mnew = defer ? mrow : fmaxf(mrow, pm);

        // p = exp(s - m), pack to bf16 dwords, write swizzled P (per-wave region)
        float ps = 0.f;
#pragma unroll
        for (int nt = 0; nt < 4; nt++) {
            float p0 = __expf(sc[nt][0] - mnew);
            float p1 = __expf(sc[nt][1] - mnew);
            float p2 = __expf(sc[nt][2] - mnew);
            float p3 = __expf(sc[nt][3] - mnew);
            ps += (p0 + p1) + (p2 + p3);
            unsigned int d0 = (unsigned int)(unsigned short)f2bf(p0)
                            | ((unsigned int)(unsigned short)f2bf(p1) << 16);
            unsigned int d1 = (unsigned int)(unsigned short)f2bf(p2)
                            | ((unsigned int)(unsigned short)f2bf(p3) << 16);
            const int cidx = (((nt * 2 + (lk >> 1)) ^ (lr & 7)) << 2) + ((lk & 1) << 1);
            Pw[cidx]     = d0;
            Pw[cidx + 1] = d1;
        }
        ps += __shfl_xor(ps, 16);
        ps += __shfl_xor(ps, 32);
        if (defer) {
            den += ps;
        } else {
            const float scale = __expf(mrow - mnew);     // first iter: exp(-inf)=0
            den = den * scale + ps;
            mrow = mnew;
#pragma unroll
            for (int r = 0; r < 4; r++) {
                const float sf = __shfl(scale, (lk << 2) + r);  // scale of q'=lk*4+r
#pragma unroll
                for (int nt2 = 0; nt2 < 4; nt2++) o[nt2][r] *= sf;
            }
        }

        // O += P V  (pa from own-wave P region; bv from V^T tile)
#pragma unroll
        for (int kk = 0; kk < 2; kk++) {
            short8 pa = *(const short8*)&Pw[((kk * 4 + lk) ^ (lr & 7)) << 2];
#pragma unroll
            for (int nt2 = 0; nt2 < 4; nt2++) {
                const int vrow = nt2 * 16 + lr;
                short8 bv = *(const short8*)&bV[vrow * 64 + (((kk * 4 + lk) ^ (vrow & 7)) * 8)];
                o[nt2] = __builtin_amdgcn_mfma_f32_16x16x32_bf16(pa, bv, o[nt2], 0, 0, 0);
            }
        }
        __syncthreads();
        cur ^= 1;
    }

    // epilogue: /= den (fetch den of q'=lk*4+r), write ctx [B,S,H*dk] bf16
#pragma unroll
    for (int r = 0; r < 4; r++) {
        const float dn = __shfl(den, (lk << 2) + r);
        const float inv = 1.f / dn;
        const int s = qt * 64 + w * 16 + (lk << 2) + r;
        const size_t base = ((size_t)b * SEQ + s) * DMODEL + h * DK;
#pragma unroll
        for (int nt2 = 0; nt2 < 4; nt2++)
            ctx[base + nt2 * 16 + lr] = f2bf(o[nt2][r] * inv);
    }
}

// ---------------- LayerNorm over D=1024; optional bf16 + f32 outputs ----------------
__global__ __launch_bounds__(256) void ln_kernel(
    const float* __restrict__ y, const float* __restrict__ g,
    const float* __restrict__ bb, short* __restrict__ out_bf,
    float* __restrict__ out_f)
{
    const int row = blockIdx.x;
    const int t = threadIdx.x;
    const float4 v = ((const float4*)(y + (size_t)row * DMODEL))[t];
    float s = v.x + v.y + v.z + v.w;
    float ss = v.x * v.x + v.y * v.y + v.z * v.z + v.w * v.w;
#pragma unroll
    for (int off = 32; off > 0; off >>= 1) {
        s  += __shfl_down(s, off);
        ss += __shfl_down(ss, off);
    }
    __shared__ float red[8];
    const int w = t >> 6, l = t & 63;
    if (l == 0) { red[w] = s; red[4 + w] = ss; }
    __syncthreads();
    s  = red[0] + red[1] + red[2] + red[3];
    ss = red[4] + red[5] + red[6] + red[7];
    const float mu = s * (1.f / DMODEL);
    const float var = ss * (1.f / DMODEL) - mu * mu;
    const float rstd = rsqrtf(var + 1e-5f);
    const float4 gg = ((const float4*)g)[t];
    const float4 bv = ((const float4*)bb)[t];
    float o0 = (v.x - mu) * rstd * gg.x + bv.x;
    float o1 = (v.y - mu) * rstd * gg.y + bv.y;
    float o2 = (v.z - mu) * rstd * gg.z + bv.z;
    float o3 = (v.w - mu) * rstd * gg.w + bv.w;
    if (out_f) ((float4*)(out_f + (size_t)row * DMODEL))[t] = make_float4(o0, o1, o2, o3);
    if (out_bf) {
        s16x4 ob = { f2bf(o0), f2bf(o1), f2bf(o2), f2bf(o3) };
        *(s16x4*)(out_bf + (size_t)row * DMODEL + t * 4) = ob;
    }
}

// ---------------- launcher ----------------
extern "C" void kernel_launch(void* const* d_in, const int* in_sizes, int n_in,
                              void* d_out, int out_size, void* d_ws, size_t ws_size,
                              hipStream_t stream)
{
    const float* x     = (const float*)d_in[0];
    const float* wq    = (const float*)d_in[1];
    const float* wk    = (const float*)d_in[2];
    const float* wv    = (const float*)d_in[3];
    const float* wo    = (const float*)d_in[4];
    const float* w1    = (const float*)d_in[5];
    const float* b1    = (const float*)d_in[6];
    const float* w2    = (const float*)d_in[7];
    const float* b2    = (const float*)d_in[8];
    const float* ln1_g = (const float*)d_in[9];
    const float* ln1_b = (const float*)d_in[10];
    const float* ln2_g = (const float*)d_in[11];
    const float* ln2_b = (const float*)d_in[12];
    const float* theta = (const float*)d_in[13];

    // workspace layout (shorts region then floats region); hb aliases q/k/v/ctx
    short* wsS   = (short*)d_ws;
    short* xb    = wsS;                    // 4,194,304
    short* wqkvT = wsS + 4194304;          // 3 x 1,048,576  (contiguous => N=3072 GEMM)
    short* woT   = wsS + 7340032;          // 1,048,576
    short* w1T   = wsS + 8388608;          // 4,194,304  [4096][1024]
    short* w2T   = wsS + 12582912;         // 4,194,304  [1024][4096]
    short* qb    = wsS + 16777216;         // q,k,v,ctx: 4 x 4,194,304 (hb alias region)
    short* ctxb  = wsS + 29360128;
    short* x1b   = wsS + 33554432;         // 4,194,304
    short* hb    = qb;                     // [4096][4096] bf16, aliases q/k/v/ctx
    float* fbase = (float*)((char*)d_ws + 75497472);
    float* y1    = fbase;                  // 4,194,304 f32 (also y2)
    float* x1f   = fbase + 4194304;        // 4,194,304 f32
    if (ws_size < 109051904) return;       // need ~109 MB

    dim3 t32(32, 8, 1);
    cast_kernel<<<4096, 256, 0, stream>>>(x, xb, 1048576);
    transpose_cast<<<dim3(32, 32), t32, 0, stream>>>(wq, wqkvT,           DMODEL, DMODEL);
    transpose_cast<<<dim3(32, 32), t32, 0, stream>>>(wk, wqkvT + 1048576, DMODEL, DMODEL);
    transpose_cast<<<dim3(32, 32), t32, 0, stream>>>(wv, wqkvT + 2097152, DMODEL, DMODEL);
    transpose_cast<<<dim3(32, 32), t32, 0, stream>>>(wo, woT,             DMODEL, DMODEL);
    transpose_cast<<<dim3(128, 32), t32, 0, stream>>>(w1, w1T, DMODEL, FDIM);
    transpose_cast<<<dim3(32, 128), t32, 0, stream>>>(w2, w2T, FDIM, DMODEL);

    // QKV: 32x24 = 768 blocks (BN=128, 3/CU)
    gemm_bt<128><<<768, 256, 0, stream>>>(xb, wqkvT, MROWS, 3072, DMODEL, MODE_QKV,
                                          nullptr, nullptr, qb);
    attn_kernel<<<1024, 256, 0, stream>>>(qb, qb + 4194304, qb + 8388608, ctxb);
    // O-proj: 32x16 = 512 blocks (BN=64, 2/CU)
    gemm_bt<64><<<512, 256, 0, stream>>>(ctxb, woT, MROWS, DMODEL, DMODEL, MODE_O,
                                         x, theta, y1);
    ln_kernel<<<4096, 256, 0, stream>>>(y1, ln1_g, ln1_b, x1b, x1f);
    // FFN-1: 32x32 = 1024 blocks (BN=128, 4/CU)
    gemm_bt<128><<<1024, 256, 0, stream>>>(x1b, w1T, MROWS, FDIM, DMODEL, MODE_H,
                                           b1, nullptr, hb);
    // FFN-2: 32x16 = 512 blocks (BN=64, 2/CU)
    gemm_bt<64><<<512, 256, 0, stream>>>(hb, w2T, MROWS, DMODEL, FDIM, MODE_F,
                                         b2, x1f, y1);
    ln_kernel<<<4096, 256, 0, stream>>>(y1, ln2_g, ln2_b, nullptr, (float*)d_out);
}